// Round 3
// baseline (15.854 us; speedup 1.0000x reference)
//
#include <hip/hip_runtime.h>

// cross_attention_89653147337302
//
// Algebraic collapse: relation = softmax(sim*50, axis=-1) has rows summing
// to exactly 1, so rel_mean = 1/4096 (constant); softmax(const) = 1/4096;
// weight = 1 + 1/4096 everywhere. The whole op is
//   out = concat(xv, xt) * (1 + 2^-12)      (exact in fp32)
//
// Pure memory-bound scaled copy: 67.1 MB traffic -> ~10.3 us @ 6.5 TB/s.
// R1 (grid-stride, 2048 wg): 15.65 us, absmax 0.0.
// R2: nontemporal builtins need native ext_vector, not HIP_vector_type.

typedef float f32x4 __attribute__((ext_vector_type(4)));

__global__ __launch_bounds__(256) void ca_scale_kernel(
    const f32x4* __restrict__ xv,
    const f32x4* __restrict__ xt,
    f32x4* __restrict__ out,
    int n4)  // float4 elements per input (1048576)
{
    const float w = 1.0f + 1.0f / 4096.0f;  // 1.000244140625, exact
    const int i = blockIdx.x * 256 + threadIdx.x;
    if (i < n4) {
        f32x4 a = __builtin_nontemporal_load(&xv[i]);
        a *= w;
        __builtin_nontemporal_store(a, &out[i]);
        f32x4 b = __builtin_nontemporal_load(&xt[i]);
        b *= w;
        __builtin_nontemporal_store(b, &out[n4 + i]);
    }
}

extern "C" void kernel_launch(void* const* d_in, const int* in_sizes, int n_in,
                              void* d_out, int out_size, void* d_ws, size_t ws_size,
                              hipStream_t stream) {
    const float* xv = (const float*)d_in[0];
    const float* xt = (const float*)d_in[1];
    float* out = (float*)d_out;

    const int n = in_sizes[0];      // 16*64*64*64 = 4194304 floats per input
    const int n4 = n >> 2;          // 1048576 float4 per input

    const int block = 256;
    const int grid = (n4 + block - 1) / block;  // 4096 wg

    ca_scale_kernel<<<grid, block, 0, stream>>>(
        (const f32x4*)xv, (const f32x4*)xt, (f32x4*)out, n4);
}